// Round 15
// baseline (147.281 us; speedup 1.0000x reference)
//
#include <hip/hip_runtime.h>
#include <hip/hip_bf16.h>

typedef __attribute__((ext_vector_type(8))) short short8;
typedef __attribute__((ext_vector_type(8))) __bf16 bf16x8;
typedef __attribute__((ext_vector_type(4))) float f32x4;
typedef __attribute__((ext_vector_type(8))) unsigned short ushort8v;
typedef __attribute__((ext_vector_type(4))) unsigned short ushort4v;

#define NB 2
#define TQ 2048
#define TKK 2048
#define EMB 1024
#define NH 16
#define HD 64

__device__ __forceinline__ unsigned short f2bf(float f){
  union { float f; unsigned u; } v; v.f = f;
  unsigned r = v.u + 0x7FFFu + ((v.u >> 16) & 1u);
  return (unsigned short)(r >> 16);
}

// async global->LDS, 16B per lane; LDS dest is wave-uniform base + lane*16
#define GLOAD_LDS16(g, l) __builtin_amdgcn_global_load_lds( \
    (const __attribute__((address_space(1))) void*)(g), \
    (__attribute__((address_space(3))) void*)(l), 16, 0, 0)

// T2 XOR swizzle for 128-byte LDS rows (involution, 16B-aligned).
// Co-designed with 128B (pow2) row pitch (round 9: 144B pitch broke it).
#define SWZ(row, inner) ((inner) ^ (((row)&7)<<4))

// Intrinsic MFMA (compiler-visible: hazard wait-states handled; inline-asm
// MFMA silently corrupted accumulators -- rounds 2-5 post-mortem).
__device__ __forceinline__ void mfma16(const short8& a, const short8& b, f32x4& c){
  c = __builtin_amdgcn_mfma_f32_16x16x32_bf16(
        __builtin_bit_cast(bf16x8, a), __builtin_bit_cast(bf16x8, b), c, 0, 0, 0);
}

// ---------------- fused prep: 2x cvt + 3x weight transpose ----------------
__device__ __forceinline__ void cvt_body(const float* __restrict__ in,
    unsigned short* __restrict__ out, int i){
  float4 v = ((const float4*)in)[i];
  ushort4v o;
  o.x = f2bf(v.x); o.y = f2bf(v.y); o.z = f2bf(v.z); o.w = f2bf(v.w);
  ((ushort4v*)out)[i] = o;
}

__device__ __forceinline__ void wt_body(const float* __restrict__ W,
    unsigned short* __restrict__ WT, int K, int N, int k0, int n0,
    unsigned short (*tile)[72]){
  int tid = threadIdx.x;
  #pragma unroll
  for (int it=0; it<4; ++it){
    int c = tid + it*256;
    int r = c>>4, c4 = (c&15)*4;
    float4 v = *(const float4*)(W + (long)(k0+r)*N + n0 + c4);
    tile[r][c4+0]=f2bf(v.x); tile[r][c4+1]=f2bf(v.y);
    tile[r][c4+2]=f2bf(v.z); tile[r][c4+3]=f2bf(v.w);
  }
  __syncthreads();
  #pragma unroll
  for (int it=0; it<2; ++it){
    int c = tid + it*256;
    int n = c>>3, k8 = (c&7)*8;
    ushort8v o;
    #pragma unroll
    for (int j=0;j<8;++j) o[j] = tile[k8+j][n];
    *(ushort8v*)(WT + (long)(n0+n)*K + k0 + k8) = o;
  }
}

// grid: [0,4096) cvt x_q | [4096,8192) cvt x_kv | [8192,8448) wt w_q |
// [8448,8960) wt w_kv | [8960,9216) wt w_proj
__global__ __launch_bounds__(256) void prep_kernel(
    const float* __restrict__ x_q, const float* __restrict__ x_kv,
    const float* __restrict__ w_q, const float* __restrict__ w_kv,
    const float* __restrict__ w_proj,
    unsigned short* __restrict__ Aq,  unsigned short* __restrict__ Akv,
    unsigned short* __restrict__ WqT, unsigned short* __restrict__ WkvT,
    unsigned short* __restrict__ WpT){
  __shared__ unsigned short tile[64][72];
  const int bx = blockIdx.x;
  if (bx < 4096){
    cvt_body(x_q, Aq, bx*256 + threadIdx.x);
  } else if (bx < 8192){
    cvt_body(x_kv, Akv, (bx-4096)*256 + threadIdx.x);
  } else if (bx < 8448){
    int blk = bx - 8192;
    wt_body(w_q, WqT, EMB, EMB, (blk>>4)*64, (blk&15)*64, tile);
  } else if (bx < 8960){
    int blk = bx - 8448;
    wt_body(w_kv, WkvT, EMB, 2*EMB, (blk>>5)*64, (blk&31)*64, tile);
  } else {
    int blk = bx - 8960;
    wt_body(w_proj, WpT, EMB, EMB, (blk>>4)*64, (blk&15)*64, tile);
  }
}

// ---------------- GEMM body: C[M,N] = A[M,K] @ BT[N,K]^T ----------------
// MODE 0: f32 out; MODE 1: bf16 out; MODE 2: V-transposed bf16 out with the
// rel-pos within-tile bias factor 2^(-(t&63)*w_rel[h]*log2e) BAKED into V'
// (Cout = VT[bh][d][t]; BT rows n0 in [EMB,2*EMB)).
template<int MODE>
__device__ __forceinline__ void gemm_body(const unsigned short* __restrict__ A,
    const unsigned short* __restrict__ BT, void* __restrict__ Cout,
    int M, int N, int K, int m0, int n0,
    unsigned short* Al, unsigned short* Bl, const float* __restrict__ w_rel){
  const int tid = threadIdx.x;
  const int wave = tid>>6, lane = tid&63;
  const int wm = (wave>>1)*64, wn = (wave&1)*64;
  const int g = lane>>4, lr = lane&15;
  const int srow = lane>>3;
  const int sinner = (lane&7)*16;
  f32x4 acc[4][4] = {};

  for (int k0=0; k0<K; k0+=64){
    #pragma unroll
    for (int j=0;j<4;++j){
      int chunk = wave*4 + j;
      int row = chunk*8 + srow;
      int kb = SWZ(row, sinner);
      GLOAD_LDS16(A + (long)(m0+row)*K + k0 + (kb>>1), Al + chunk*512);
      GLOAD_LDS16(BT + (long)(n0+row)*K + k0 + (kb>>1), Bl + chunk*512);
    }
    __syncthreads();
    #pragma unroll
    for (int kk=0;kk<2;++kk){
      short8 af[4], bfr[4];
      const int kbyte = kk*64 + g*16;
      #pragma unroll
      for (int i=0;i<4;++i){
        int ar = wm + i*16 + lr;
        af[i] = *(const short8*)((const char*)Al + ar*128 + SWZ(ar, kbyte));
        int br = wn + i*16 + lr;
        bfr[i] = *(const short8*)((const char*)Bl + br*128 + SWZ(br, kbyte));
      }
      #pragma unroll
      for (int i=0;i<4;++i)
        #pragma unroll
        for (int jn=0;jn<4;++jn)
          mfma16(af[i], bfr[jn], acc[i][jn]);
    }
    __syncthreads();
  }
  #pragma unroll
  for (int i=0;i<4;++i){
    int row = m0 + wm + i*16 + g*4;
    #pragma unroll
    for (int jn=0;jn<4;++jn){
      if (MODE == 2){
        int dg = n0 - EMB + wn + jn*16 + lr;
        int h = dg >> 6, d = dg & 63;
        int b = row >> 11, t = row & (TKK-1);
        // bake c(tloc) = 2^(-(t&63)*wr2); t%4==0 so (t&63)+3 never wraps
        float wr2h = w_rel[h]*1.44269504f;
        float fac = exp2f(-(float)(t & 63)*wr2h);
        float stp = exp2f(-wr2h);
        ushort4v w;
        #pragma unroll
        for (int r=0;r<4;++r){ w[r] = f2bf(acc[i][jn][r]*fac); fac *= stp; }
        *(ushort4v*)((unsigned short*)Cout + ((long)((b*NH + h)*HD + d)*TKK + t)) = w;
      } else {
        int col = n0 + wn + jn*16 + lr;
        #pragma unroll
        for (int r=0;r<4;++r){
          if (MODE == 1)
            ((unsigned short*)Cout)[(long)(row+r)*N + col] = f2bf(acc[i][jn][r]);
          else
            ((float*)Cout)[(long)(row+r)*N + col] = acc[i][jn][r];
        }
      }
    }
  }
}

// Fused Q-proj + K-proj + V-proj(transposed+bias-baked) -- 768 blocks, 3/CU.
// XCD swizzle: logical x%8 == hw-linear%8 -> each XCD owns 3 B-panels.
__global__ __launch_bounds__(256,3) void gemm_qkv(
    const unsigned short* __restrict__ Aq,  const unsigned short* __restrict__ WqT,  unsigned short* __restrict__ Qb,
    const unsigned short* __restrict__ Akv, const unsigned short* __restrict__ WkvT,
    unsigned short* __restrict__ Kb, unsigned short* __restrict__ VT,
    const float* __restrict__ w_rel){
  __shared__ unsigned short Al[128*64];
  __shared__ unsigned short Bl[128*64];
  const int p = blockIdx.x + 24*blockIdx.y;        // hw linear id
  const int x = (p & 7) + 8*((p >> 3) % 3);        // bijective remap
  const int y = (p >> 3) / 3;
  if (x < 8)
    gemm_body<1>(Aq,  WqT,  Qb, NB*TQ, EMB, EMB, y*128, x*128, Al, Bl, nullptr);
  else if (x < 16)
    gemm_body<1>(Akv, WkvT, Kb, NB*TKK, EMB, EMB, y*128, (x-8)*128, Al, Bl, nullptr);
  else
    gemm_body<2>(Akv, WkvT, VT, NB*TKK, EMB, EMB, y*128, EMB + (x-16)*128, Al, Bl, w_rel);
}

// ---------------- out-proj GEMM, 64x128 tile (512 blocks -> 2/CU) ----------------
__global__ __launch_bounds__(256,2) void gemm_out(const unsigned short* __restrict__ A,
    const unsigned short* __restrict__ BT, float* __restrict__ C,
    int M, int N, int K){
  __shared__ unsigned short Al[64*64];
  __shared__ unsigned short Bl[128*64];
  const int tid = threadIdx.x;
  const int wave = tid>>6, lane = tid&63;
  const int m0 = blockIdx.y*64, n0 = blockIdx.x*128;
  const int wm = (wave>>1)*32, wn = (wave&1)*64;
  const int g = lane>>4, lr = lane&15;
  const int srow = lane>>3;
  const int sinner = (lane&7)*16;
  f32x4 acc[2][4] = {};

  for (int k0=0; k0<K; k0+=64){
    #pragma unroll
    for (int j=0;j<2;++j){
      int chunk = wave*2 + j;
      int row = chunk*8 + srow;
      int kb = SWZ(row, sinner);
      GLOAD_LDS16(A + (long)(m0+row)*K + k0 + (kb>>1), Al + chunk*512);
    }
    #pragma unroll
    for (int j=0;j<4;++j){
      int chunk = wave*4 + j;
      int row = chunk*8 + srow;
      int kb = SWZ(row, sinner);
      GLOAD_LDS16(BT + (long)(n0+row)*K + k0 + (kb>>1), Bl + chunk*512);
    }
    __syncthreads();
    #pragma unroll
    for (int kk=0;kk<2;++kk){
      short8 af[2], bfr[4];
      const int kbyte = kk*64 + g*16;
      #pragma unroll
      for (int i=0;i<2;++i){
        int ar = wm + i*16 + lr;
        af[i] = *(const short8*)((const char*)Al + ar*128 + SWZ(ar, kbyte));
      }
      #pragma unroll
      for (int jn=0;jn<4;++jn){
        int br = wn + jn*16 + lr;
        bfr[jn] = *(const short8*)((const char*)Bl + br*128 + SWZ(br, kbyte));
      }
      #pragma unroll
      for (int i=0;i<2;++i)
        #pragma unroll
        for (int jn=0;jn<4;++jn)
          mfma16(af[i], bfr[jn], acc[i][jn]);
    }
    __syncthreads();
  }
  #pragma unroll
  for (int i=0;i<2;++i){
    int row = m0 + wm + i*16 + g*4;
    #pragma unroll
    for (int jn=0;jn<4;++jn){
      int col = n0 + wn + jn*16 + lr;
      #pragma unroll
      for (int r=0;r<4;++r)
        C[(long)(row+r)*N + col] = acc[i][jn][r];
    }
  }
}

// ---------------- flash attention, swapped-QK^T, in-lane softmax ----------------
// 4 waves x 32 q-rows (two 16-row m-fragments) = 128 q per block. Halves the
// K/V LDS read amplification vs 8x16 (kf/vf reads reused across both m-frags)
// -- attn was LDS-read-throughput-bound (round-14 post-mortem arithmetic).
// KV tile = 64, triple-buffered, counted vmcnt. Bias algebraic as round 14.
__global__ __launch_bounds__(256,2) void attn_kernel(const unsigned short* __restrict__ Qb,
    const unsigned short* __restrict__ Kb, const unsigned short* __restrict__ VT,
    const float* __restrict__ w_rel, unsigned short* __restrict__ Ob){
  __shared__ unsigned short Kl[3][64*64];   // [buf][t][d] swizzled, 128B rows
  __shared__ unsigned short Vl[3][64*64];   // [buf][d][t] swizzled, 128B rows
  __shared__ __attribute__((aligned(16))) char Pl[4][32*128];  // per-wave P, 32 rows
  // XCD-chunked swizzle (bijective, 512 blocks): 4 bh (2MB K+V) per XCD L2.
  const int id  = blockIdx.x + 16*blockIdx.y;
  const int nid = (id & 7)*64 + (id >> 3);
  const int qb  = nid & 15, bh = nid >> 4;
  const int b = bh>>4, h = bh&15;
  const int q0 = qb*128;
  const int tid = threadIdx.x, wave = tid>>6, lane = tid&63;
  const int g = lane>>4, lr = lane&15;
  const int srow = lane>>3, sinner = (lane&7)*16;
  const float C1 = 0.125f*1.44269504f;        // SCALE * log2(e)
  const float wr2 = w_rel[h]*1.44269504f;     // bias in log2 domain
  const float w64 = 64.0f*wr2;
  char* Pw = &Pl[wave][0];

  // staging: each wave covers 16 rows (two 8-row groups; row+8 keeps (row&7)
  // so the same swizzled lane offset applies to both groups)
  const int strow = wave*16 + srow;
  const int skb = SWZ(strow, sinner);
  const unsigned short* Kg  = Kb + (long)(b*TKK + strow)*EMB + h*HD + (skb>>1);
  const unsigned short* Vg  = VT + (long)(bh*HD + strow)*TKK + (skb>>1);
  const unsigned short* Kg2 = Kg + (long)8*EMB;
  const unsigned short* Vg2 = Vg + (long)8*TKK;

  // Q fragments (B-operand: col = q = lr, k = kk*32 + g*8), m = q-16-block
  short8 qf[2][2];
  #pragma unroll
  for (int m=0;m<2;++m)
    #pragma unroll
    for (int kk=0;kk<2;++kk)
      qf[m][kk] = *(const short8*)(Qb + (long)(b*TQ + q0 + wave*32 + m*16 + lr)*EMB + h*HD + kk*32 + g*8);

  // L-vector fragment: B[k][*] = 2^(-k*wr2), k = kk*32 + g*8 + j
  short8 cfrag[2];
  #pragma unroll
  for (int kk=0;kk<2;++kk)
    #pragma unroll
    for (int j=0;j<8;++j)
      cfrag[kk][j] = (short)f2bf(exp2f(-(float)(kk*32 + g*8 + j)*wr2));

  f32x4 oacc[2][4] = {};
  f32x4 lacc[2] = {};
  float Mxs[2] = {-1e30f, -1e30f};  // running max, s*C1 domain (shift +w64/tile)

  // prologue: stage tiles 0,1 into bufs 0,1 (8 ops); wait tile 0's 4
  GLOAD_LDS16(Kg,  &Kl[0][wave*1024]);
  GLOAD_LDS16(Kg2, &Kl[0][wave*1024+512]);
  GLOAD_LDS16(Vg,  &Vl[0][wave*1024]);
  GLOAD_LDS16(Vg2, &Vl[0][wave*1024+512]);
  GLOAD_LDS16(Kg  + (long)64*EMB, &Kl[1][wave*1024]);
  GLOAD_LDS16(Kg2 + (long)64*EMB, &Kl[1][wave*1024+512]);
  GLOAD_LDS16(Vg  + 64, &Vl[1][wave*1024]);
  GLOAD_LDS16(Vg2 + 64, &Vl[1][wave*1024+512]);
  asm volatile("s_waitcnt vmcnt(4)" ::: "memory");
  __builtin_amdgcn_s_barrier();

  int cur = 0;
  for (int kt=0; kt<TKK; kt+=64){
    // prefetch tile t+2 into buf (cur+2)%3 (4 loads)
    const bool issue = (kt + 128 < TKK);
    int nxt2 = cur + 2; if (nxt2 >= 3) nxt2 -= 3;
    if (issue){
      GLOAD_LDS16(Kg  + (long)(kt+128)*EMB, &Kl[nxt2][wave*1024]);
      GLOAD_LDS16(Kg2 + (long)(kt+128)*EMB, &Kl[nxt2][wave*1024+512]);
      GLOAD_LDS16(Vg  + (kt+128), &Vl[nxt2][wave*1024]);
      GLOAD_LDS16(Vg2 + (kt+128), &Vl[nxt2][wave*1024+512]);
    }

    // S^T = K Q^T : lane (g,lr) gets S[q = m*16+lr][t-local = n*16+4g+r]
    f32x4 sacc[2][4] = {};
    __builtin_amdgcn_s_setprio(1);
    #pragma unroll
    for (int kk=0;kk<2;++kk){
      short8 kf[4];
      const int kbyte = kk*64 + g*16;
      #pragma unroll
      for (int n=0;n<4;++n){
        int trow = n*16 + lr;
        kf[n] = *(const short8*)((const char*)&Kl[cur][0] + trow*128 + SWZ(trow, kbyte));
      }
      #pragma unroll
      for (int n=0;n<4;++n)
        #pragma unroll
        for (int m=0;m<2;++m)
          mfma16(kf[n], qf[m][kk], sacc[m][n]);
    }
    __builtin_amdgcn_s_setprio(0);

    // per-m in-lane max over 16 raw scores, then cross-g
    float rs[2];
    #pragma unroll
    for (int m=0;m<2;++m){
      float m0 = fmaxf(fmaxf(sacc[m][0][0],sacc[m][0][1]),sacc[m][0][2]);
      float m1 = fmaxf(fmaxf(sacc[m][0][3],sacc[m][1][0]),sacc[m][1][1]);
      float m2 = fmaxf(fmaxf(sacc[m][1][2],sacc[m][1][3]),sacc[m][2][0]);
      float m3 = fmaxf(fmaxf(sacc[m][2][1],sacc[m][2][2]),sacc[m][2][3]);
      float m4 = fmaxf(fmaxf(sacc[m][3][0],sacc[m][3][1]),sacc[m][3][2]);
      float a  = fmaxf(fmaxf(m0,m1),m2);
      float bb = fmaxf(fmaxf(m3,m4),sacc[m][3][3]);
      float rowmax = fmaxf(a,bb);
      rowmax = fmaxf(rowmax, __shfl_xor(rowmax, 16, 64));
      rowmax = fmaxf(rowmax, __shfl_xor(rowmax, 32, 64));
      rs[m] = rowmax*C1;   // C1 > 0: max commutes with the scale
    }

    // defer-max: rescale only when max grew by > 8 (log2 units; P <= 2^8)
    int grew = (rs[0] > Mxs[0] + 8.0f) | (rs[1] > Mxs[1] + 8.0f);
    if (__any(grew)){
      #pragma unroll
      for (int m=0;m<2;++m){
        float Mn = fmaxf(Mxs[m], rs[m]);
        float rf = exp2f(Mxs[m] - Mn);
        Mxs[m] = Mn;
        float rfo[4];
        #pragma unroll
        for (int r=0;r<4;++r) rfo[r] = __shfl(rf, 4*g + r, 64);  // rf for q-local=4g+r
        #pragma unroll
        for (int n=0;n<4;++n)
          #pragma unroll
          for (int r=0;r<4;++r) oacc[m][n][r] *= rfo[r];
        #pragma unroll
        for (int r=0;r<4;++r) lacc[m][r] *= rfo[r];
      }
    }

    // P = exp2(s*C1 - Mxs) -> bf16, 8B stores, 128B pitch; row = m*16+lr
    #pragma unroll
    for (int m=0;m<2;++m)
      #pragma unroll
      for (int n=0;n<4;++n){
        ushort4v w;
        #pragma unroll
        for (int r=0;r<4;++r)
          w[r] = __builtin_bit_cast(unsigned short,
                   __float2bfloat16(exp2f(fmaf(sacc[m][n][r], C1, -Mxs[m]))));
        *(ushort4v*)(Pw + (m*16+lr)*128 + SWZ(lr, 32*n + 8*g)) = w;
      }

    // compiler fence only: P is per-wave private; HW DS ops in-order per wave
    asm volatile("" ::: "memory");

    // O += P @ V' ; L += P @ cfrag  (rows q=4g+r per m, cols d=n*16+lr)
    __builtin_amdgcn_s_setprio(1);
    #pragma unroll
    for (int kk=0;kk<2;++kk){
      const int kbyte = kk*64 + g*16;
      short8 pf[2];
      #pragma unroll
      for (int m=0;m<2;++m)
        pf[m] = *(const short8*)(Pw + (m*16+lr)*128 + SWZ(lr, kbyte));
      #pragma unroll
      for (int n=0;n<4;++n){
        int vrow = n*16 + lr;
        short8 vf = *(const short8*)((const char*)&Vl[cur][0] + vrow*128 + SWZ(vrow, kbyte));
        #pragma unroll
        for (int m=0;m<2;++m)
          mfma16(pf[m], vf, oacc[m][n]);
      }
      #pragma unroll
      for (int m=0;m<2;++m)
        mfma16(pf[m], cfrag[kk], lacc[m]);
    }
    __builtin_amdgcn_s_setprio(0);

    // next tile's uniform bias shift
    Mxs[0] += w64; Mxs[1] += w64;

    // counted wait: retire t+1's 4 loads (t+2's stay in flight) + barrier.
    if (issue) asm volatile("s_waitcnt vmcnt(4) lgkmcnt(0)" ::: "memory");
    else       asm volatile("s_waitcnt vmcnt(0) lgkmcnt(0)" ::: "memory");
    __builtin_amdgcn_s_barrier();
    cur += 1; if (cur >= 3) cur -= 3;
  }

  // epilogue: O / L -> bf16  (row q = m*16 + 4g+r, col d = n*16+lr)
  #pragma unroll
  for (int m=0;m<2;++m)
    #pragma unroll
    for (int r=0;r<4;++r){
      float inv = 1.0f / lacc[m][r];
      int q = q0 + wave*32 + m*16 + 4*g + r;
      #pragma unroll
      for (int n=0;n<4;++n){
        int d = n*16 + lr;
        Ob[(long)(b*TQ + q)*EMB + h*HD + d] = f2bf(oacc[m][n][r]*inv);
      }
    }
}

extern "C" void kernel_launch(void* const* d_in, const int* in_sizes, int n_in,
                              void* d_out, int out_size, void* d_ws, size_t ws_size,
                              hipStream_t stream){
  const float* x_q    = (const float*)d_in[0];
  const float* x_kv   = (const float*)d_in[1];
  const float* w_q    = (const float*)d_in[2];
  const float* w_kv   = (const float*)d_in[3];
  const float* w_proj = (const float*)d_in[4];
  const float* w_rel  = (const float*)d_in[5];
  (void)in_sizes; (void)n_in; (void)out_size; (void)ws_size;
  char* ws = (char*)d_ws;
  const size_t MB = 1024*1024;
  unsigned short* Qb   = (unsigned short*)(ws + 0);       // 8 MB
  unsigned short* Kb   = (unsigned short*)(ws + 8*MB);    // 8 MB (K only, pitch EMB)
  unsigned short* VT   = (unsigned short*)(ws + 16*MB);   // 8 MB (V' transposed, bias-baked)
  unsigned short* WpT  = (unsigned short*)(ws + 24*MB);   // 2 MB
  unsigned short* WqT  = (unsigned short*)(ws + 26*MB);   // 2 MB
  unsigned short* WkvT = (unsigned short*)(ws + 28*MB);   // 4 MB
  unsigned short* Aq   = (unsigned short*)(ws + 32*MB);   // 8 MB, dead after gemm_qkv
  unsigned short* Akv  = (unsigned short*)(ws + 40*MB);   // 8 MB, dead after gemm_qkv
  unsigned short* Ob   = Aq;    // reuse (lifetimes disjoint)
  float* out = (float*)d_out;

  prep_kernel<<<9216, 256, 0, stream>>>(x_q, x_kv, w_q, w_kv, w_proj,
                                        Aq, Akv, WqT, WkvT, WpT);
  gemm_qkv<<<dim3(24,32), 256, 0, stream>>>(Aq, WqT, Qb, Akv, WkvT, Kb, VT, w_rel);
  attn_kernel<<<dim3(16,32), 256, 0, stream>>>(Qb, Kb, VT, w_rel, Ob);
  gemm_out<<<dim3(8,64), 256, 0, stream>>>(Ob, WpT, out, NB*TQ, EMB, EMB);
}

// Round 16
// 141.520 us; speedup vs baseline: 1.0407x; 1.0407x over previous
//
#include <hip/hip_runtime.h>
#include <hip/hip_bf16.h>

typedef __attribute__((ext_vector_type(8))) short short8;
typedef __attribute__((ext_vector_type(8))) __bf16 bf16x8;
typedef __attribute__((ext_vector_type(4))) float f32x4;
typedef __attribute__((ext_vector_type(8))) unsigned short ushort8v;
typedef __attribute__((ext_vector_type(4))) unsigned short ushort4v;

#define NB 2
#define TQ 2048
#define TKK 2048
#define EMB 1024
#define NH 16
#define HD 64

__device__ __forceinline__ unsigned short f2bf(float f){
  union { float f; unsigned u; } v; v.f = f;
  unsigned r = v.u + 0x7FFFu + ((v.u >> 16) & 1u);
  return (unsigned short)(r >> 16);
}

// async global->LDS, 16B per lane; LDS dest is wave-uniform base + lane*16
#define GLOAD_LDS16(g, l) __builtin_amdgcn_global_load_lds( \
    (const __attribute__((address_space(1))) void*)(g), \
    (__attribute__((address_space(3))) void*)(l), 16, 0, 0)

// T2 XOR swizzle for 128-byte LDS rows (involution, 16B-aligned).
// Co-designed with 128B (pow2) row pitch (round 9: 144B pitch broke it).
#define SWZ(row, inner) ((inner) ^ (((row)&7)<<4))

// Intrinsic MFMA (compiler-visible: hazard wait-states handled; inline-asm
// MFMA silently corrupted accumulators -- rounds 2-5 post-mortem).
__device__ __forceinline__ void mfma16(const short8& a, const short8& b, f32x4& c){
  c = __builtin_amdgcn_mfma_f32_16x16x32_bf16(
        __builtin_bit_cast(bf16x8, a), __builtin_bit_cast(bf16x8, b), c, 0, 0, 0);
}

// ---------------- fused prep: 2x cvt + 3x weight transpose ----------------
__device__ __forceinline__ void cvt_body(const float* __restrict__ in,
    unsigned short* __restrict__ out, int i){
  float4 v = ((const float4*)in)[i];
  ushort4v o;
  o.x = f2bf(v.x); o.y = f2bf(v.y); o.z = f2bf(v.z); o.w = f2bf(v.w);
  ((ushort4v*)out)[i] = o;
}

__device__ __forceinline__ void wt_body(const float* __restrict__ W,
    unsigned short* __restrict__ WT, int K, int N, int k0, int n0,
    unsigned short (*tile)[72]){
  int tid = threadIdx.x;
  #pragma unroll
  for (int it=0; it<4; ++it){
    int c = tid + it*256;
    int r = c>>4, c4 = (c&15)*4;
    float4 v = *(const float4*)(W + (long)(k0+r)*N + n0 + c4);
    tile[r][c4+0]=f2bf(v.x); tile[r][c4+1]=f2bf(v.y);
    tile[r][c4+2]=f2bf(v.z); tile[r][c4+3]=f2bf(v.w);
  }
  __syncthreads();
  #pragma unroll
  for (int it=0; it<2; ++it){
    int c = tid + it*256;
    int n = c>>3, k8 = (c&7)*8;
    ushort8v o;
    #pragma unroll
    for (int j=0;j<8;++j) o[j] = tile[k8+j][n];
    *(ushort8v*)(WT + (long)(n0+n)*K + k0 + k8) = o;
  }
}

// grid: [0,4096) cvt x_q | [4096,8192) cvt x_kv | [8192,8448) wt w_q |
// [8448,8960) wt w_kv | [8960,9216) wt w_proj
__global__ __launch_bounds__(256) void prep_kernel(
    const float* __restrict__ x_q, const float* __restrict__ x_kv,
    const float* __restrict__ w_q, const float* __restrict__ w_kv,
    const float* __restrict__ w_proj,
    unsigned short* __restrict__ Aq,  unsigned short* __restrict__ Akv,
    unsigned short* __restrict__ WqT, unsigned short* __restrict__ WkvT,
    unsigned short* __restrict__ WpT){
  __shared__ unsigned short tile[64][72];
  const int bx = blockIdx.x;
  if (bx < 4096){
    cvt_body(x_q, Aq, bx*256 + threadIdx.x);
  } else if (bx < 8192){
    cvt_body(x_kv, Akv, (bx-4096)*256 + threadIdx.x);
  } else if (bx < 8448){
    int blk = bx - 8192;
    wt_body(w_q, WqT, EMB, EMB, (blk>>4)*64, (blk&15)*64, tile);
  } else if (bx < 8960){
    int blk = bx - 8448;
    wt_body(w_kv, WkvT, EMB, 2*EMB, (blk>>5)*64, (blk&31)*64, tile);
  } else {
    int blk = bx - 8960;
    wt_body(w_proj, WpT, EMB, EMB, (blk>>4)*64, (blk&15)*64, tile);
  }
}

// ---------------- GEMM body: C[M,N] = A[M,K] @ BT[N,K]^T ----------------
// MODE 0: f32 out; MODE 1: bf16 out; MODE 2: V-transposed bf16 out with the
// rel-pos within-tile bias factor 2^(-(t&63)*w_rel[h]*log2e) BAKED into V'
// (Cout = VT[bh][d][t]; BT rows n0 in [EMB,2*EMB)).
template<int MODE>
__device__ __forceinline__ void gemm_body(const unsigned short* __restrict__ A,
    const unsigned short* __restrict__ BT, void* __restrict__ Cout,
    int M, int N, int K, int m0, int n0,
    unsigned short* Al, unsigned short* Bl, const float* __restrict__ w_rel){
  const int tid = threadIdx.x;
  const int wave = tid>>6, lane = tid&63;
  const int wm = (wave>>1)*64, wn = (wave&1)*64;
  const int g = lane>>4, lr = lane&15;
  const int srow = lane>>3;
  const int sinner = (lane&7)*16;
  f32x4 acc[4][4] = {};

  for (int k0=0; k0<K; k0+=64){
    #pragma unroll
    for (int j=0;j<4;++j){
      int chunk = wave*4 + j;
      int row = chunk*8 + srow;
      int kb = SWZ(row, sinner);
      GLOAD_LDS16(A + (long)(m0+row)*K + k0 + (kb>>1), Al + chunk*512);
      GLOAD_LDS16(BT + (long)(n0+row)*K + k0 + (kb>>1), Bl + chunk*512);
    }
    __syncthreads();
    #pragma unroll
    for (int kk=0;kk<2;++kk){
      short8 af[4], bfr[4];
      const int kbyte = kk*64 + g*16;
      #pragma unroll
      for (int i=0;i<4;++i){
        int ar = wm + i*16 + lr;
        af[i] = *(const short8*)((const char*)Al + ar*128 + SWZ(ar, kbyte));
        int br = wn + i*16 + lr;
        bfr[i] = *(const short8*)((const char*)Bl + br*128 + SWZ(br, kbyte));
      }
      #pragma unroll
      for (int i=0;i<4;++i)
        #pragma unroll
        for (int jn=0;jn<4;++jn)
          mfma16(af[i], bfr[jn], acc[i][jn]);
    }
    __syncthreads();
  }
  #pragma unroll
  for (int i=0;i<4;++i){
    int row = m0 + wm + i*16 + g*4;
    #pragma unroll
    for (int jn=0;jn<4;++jn){
      if (MODE == 2){
        int dg = n0 - EMB + wn + jn*16 + lr;
        int h = dg >> 6, d = dg & 63;
        int b = row >> 11, t = row & (TKK-1);
        // bake c(tloc) = 2^(-(t&63)*wr2); t%4==0 so (t&63)+3 never wraps
        float wr2h = w_rel[h]*1.44269504f;
        float fac = exp2f(-(float)(t & 63)*wr2h);
        float stp = exp2f(-wr2h);
        ushort4v w;
        #pragma unroll
        for (int r=0;r<4;++r){ w[r] = f2bf(acc[i][jn][r]*fac); fac *= stp; }
        *(ushort4v*)((unsigned short*)Cout + ((long)((b*NH + h)*HD + d)*TKK + t)) = w;
      } else {
        int col = n0 + wn + jn*16 + lr;
        #pragma unroll
        for (int r=0;r<4;++r){
          if (MODE == 1)
            ((unsigned short*)Cout)[(long)(row+r)*N + col] = f2bf(acc[i][jn][r]);
          else
            ((float*)Cout)[(long)(row+r)*N + col] = acc[i][jn][r];
        }
      }
    }
  }
}

// Fused Q-proj + K-proj + V-proj(transposed+bias-baked) -- 768 blocks, 3/CU.
// XCD swizzle: logical x%8 == hw-linear%8 -> each XCD owns 3 B-panels.
__global__ __launch_bounds__(256,3) void gemm_qkv(
    const unsigned short* __restrict__ Aq,  const unsigned short* __restrict__ WqT,  unsigned short* __restrict__ Qb,
    const unsigned short* __restrict__ Akv, const unsigned short* __restrict__ WkvT,
    unsigned short* __restrict__ Kb, unsigned short* __restrict__ VT,
    const float* __restrict__ w_rel){
  __shared__ unsigned short Al[128*64];
  __shared__ unsigned short Bl[128*64];
  const int p = blockIdx.x + 24*blockIdx.y;        // hw linear id
  const int x = (p & 7) + 8*((p >> 3) % 3);        // bijective remap
  const int y = (p >> 3) / 3;
  if (x < 8)
    gemm_body<1>(Aq,  WqT,  Qb, NB*TQ, EMB, EMB, y*128, x*128, Al, Bl, nullptr);
  else if (x < 16)
    gemm_body<1>(Akv, WkvT, Kb, NB*TKK, EMB, EMB, y*128, (x-8)*128, Al, Bl, nullptr);
  else
    gemm_body<2>(Akv, WkvT, VT, NB*TKK, EMB, EMB, y*128, EMB + (x-16)*128, Al, Bl, w_rel);
}

// ---------------- out-proj GEMM, 64x128 tile (512 blocks -> 2/CU) ----------------
__global__ __launch_bounds__(256,2) void gemm_out(const unsigned short* __restrict__ A,
    const unsigned short* __restrict__ BT, float* __restrict__ C,
    int M, int N, int K){
  __shared__ unsigned short Al[64*64];
  __shared__ unsigned short Bl[128*64];
  const int tid = threadIdx.x;
  const int wave = tid>>6, lane = tid&63;
  const int m0 = blockIdx.y*64, n0 = blockIdx.x*128;
  const int wm = (wave>>1)*32, wn = (wave&1)*64;
  const int g = lane>>4, lr = lane&15;
  const int srow = lane>>3;
  const int sinner = (lane&7)*16;
  f32x4 acc[2][4] = {};

  for (int k0=0; k0<K; k0+=64){
    #pragma unroll
    for (int j=0;j<2;++j){
      int chunk = wave*2 + j;
      int row = chunk*8 + srow;
      int kb = SWZ(row, sinner);
      GLOAD_LDS16(A + (long)(m0+row)*K + k0 + (kb>>1), Al + chunk*512);
    }
    #pragma unroll
    for (int j=0;j<4;++j){
      int chunk = wave*4 + j;
      int row = chunk*8 + srow;
      int kb = SWZ(row, sinner);
      GLOAD_LDS16(BT + (long)(n0+row)*K + k0 + (kb>>1), Bl + chunk*512);
    }
    __syncthreads();
    #pragma unroll
    for (int kk=0;kk<2;++kk){
      short8 af[2], bfr[4];
      const int kbyte = kk*64 + g*16;
      #pragma unroll
      for (int i=0;i<2;++i){
        int ar = wm + i*16 + lr;
        af[i] = *(const short8*)((const char*)Al + ar*128 + SWZ(ar, kbyte));
      }
      #pragma unroll
      for (int jn=0;jn<4;++jn){
        int br = wn + jn*16 + lr;
        bfr[jn] = *(const short8*)((const char*)Bl + br*128 + SWZ(br, kbyte));
      }
      #pragma unroll
      for (int i=0;i<2;++i)
        #pragma unroll
        for (int jn=0;jn<4;++jn)
          mfma16(af[i], bfr[jn], acc[i][jn]);
    }
    __syncthreads();
  }
  #pragma unroll
  for (int i=0;i<2;++i){
    int row = m0 + wm + i*16 + g*4;
    #pragma unroll
    for (int jn=0;jn<4;++jn){
      int col = n0 + wn + jn*16 + lr;
      #pragma unroll
      for (int r=0;r<4;++r)
        C[(long)(row+r)*N + col] = acc[i][jn][r];
    }
  }
}

// ---------------- flash attention, swapped-QK^T, in-lane softmax ----------------
// 8 waves x 16 q-rows (r14-proven per-half code), KVBLK=128 per iteration as
// two 64-t halves -> 16 loop iterations instead of 32: per-iteration fixed
// costs (barrier coupling, waitcnt, prefetch branch, rescale scaffolding)
// halved -- the only lever that ever moved attn was barrier-count (r10).
// Half-B bias: P_B uses Mxs+w64 (exact, same factorization proof as r14).
__global__ __launch_bounds__(512,4) void attn_kernel(const unsigned short* __restrict__ Qb,
    const unsigned short* __restrict__ Kb, const unsigned short* __restrict__ VT,
    const float* __restrict__ w_rel, unsigned short* __restrict__ Ob){
  __shared__ unsigned short Kl[2][2][64*64];  // [buf][half][t][d] swizzled
  __shared__ unsigned short Vl[2][2][64*64];  // [buf][half][d][t] swizzled
  __shared__ __attribute__((aligned(16))) char Pl[8][16*128];  // per-wave P
  // XCD-chunked swizzle (bijective, 512 blocks): 4 bh (2MB K+V) per XCD L2.
  const int id  = blockIdx.x + 16*blockIdx.y;
  const int nid = (id & 7)*64 + (id >> 3);
  const int qb  = nid & 15, bh = nid >> 4;
  const int b = bh>>4, h = bh&15;
  const int q0 = qb*128;
  const int tid = threadIdx.x, wave = tid>>6, lane = tid&63;
  const int g = lane>>4, lr = lane&15;
  const int srow = lane>>3, sinner = (lane&7)*16;
  const float C1 = 0.125f*1.44269504f;        // SCALE * log2(e)
  const float wr2 = w_rel[h]*1.44269504f;     // bias in log2 domain
  const float w64 = 64.0f*wr2;
  char* Pw = &Pl[wave][0];

  // staging: each wave covers 8 rows of each 64-row half (8 lanes x 16B/row)
  const int strow = wave*8 + srow;
  const int skb = SWZ(strow, sinner);
  const unsigned short* Kg = Kb + (long)(b*TKK + strow)*EMB + h*HD + (skb>>1);
  const unsigned short* Vg = VT + (long)(bh*HD + strow)*TKK + (skb>>1);

  // Q fragment (B-operand: col = q = lr, k = kk*32 + g*8)
  short8 qf[2];
  #pragma unroll
  for (int kk=0;kk<2;++kk)
    qf[kk] = *(const short8*)(Qb + (long)(b*TQ + q0 + wave*16 + lr)*EMB + h*HD + kk*32 + g*8);

  // L-vector fragment: B[k][*] = 2^(-k*wr2), k = kk*32 + g*8 + j
  short8 cfrag[2];
  #pragma unroll
  for (int kk=0;kk<2;++kk)
    #pragma unroll
    for (int j=0;j<8;++j)
      cfrag[kk][j] = (short)f2bf(exp2f(-(float)(kk*32 + g*8 + j)*wr2));

  f32x4 oacc[4] = {};
  f32x4 lacc = {};
  float Mxs = -1e30f;   // running max, s*C1 domain (shifts +2*w64 per iter)

  // prologue: stage iter 0 (both halves) into buf 0
  GLOAD_LDS16(Kg,                 &Kl[0][0][wave*512]);
  GLOAD_LDS16(Kg + (long)64*EMB,  &Kl[0][1][wave*512]);
  GLOAD_LDS16(Vg,                 &Vl[0][0][wave*512]);
  GLOAD_LDS16(Vg + 64,            &Vl[0][1][wave*512]);
  asm volatile("s_waitcnt vmcnt(0)" ::: "memory");
  __builtin_amdgcn_s_barrier();

  int cur = 0;
  for (int kt=0; kt<TKK; kt+=128){
    // prefetch next 128-t iteration into buf cur^1 (lands by end of iter)
    if (kt + 128 < TKK){
      GLOAD_LDS16(Kg + (long)(kt+128)*EMB,    &Kl[cur^1][0][wave*512]);
      GLOAD_LDS16(Kg + (long)(kt+192)*EMB,    &Kl[cur^1][1][wave*512]);
      GLOAD_LDS16(Vg + (kt+128),              &Vl[cur^1][0][wave*512]);
      GLOAD_LDS16(Vg + (kt+192),              &Vl[cur^1][1][wave*512]);
    }

    // S^T = K Q^T for both halves: lane (g,lr) gets S[q=lr][t = n*16+4g+r]
    f32x4 sacc[2][4] = {};
    __builtin_amdgcn_s_setprio(1);
    #pragma unroll
    for (int hf=0;hf<2;++hf)
      #pragma unroll
      for (int kk=0;kk<2;++kk){
        short8 kf[4];
        const int kbyte = kk*64 + g*16;
        #pragma unroll
        for (int n=0;n<4;++n){
          int trow = n*16 + lr;
          kf[n] = *(const short8*)((const char*)&Kl[cur][hf][0] + trow*128 + SWZ(trow, kbyte));
        }
        #pragma unroll
        for (int n=0;n<4;++n)
          mfma16(kf[n], qf[kk], sacc[hf][n]);
      }
    __builtin_amdgcn_s_setprio(0);

    // per-half in-lane max over 16 raw scores, then cross-g
    float rs[2];
    #pragma unroll
    for (int hf=0;hf<2;++hf){
      float m0 = fmaxf(fmaxf(sacc[hf][0][0],sacc[hf][0][1]),sacc[hf][0][2]);
      float m1 = fmaxf(fmaxf(sacc[hf][0][3],sacc[hf][1][0]),sacc[hf][1][1]);
      float m2 = fmaxf(fmaxf(sacc[hf][1][2],sacc[hf][1][3]),sacc[hf][2][0]);
      float m3 = fmaxf(fmaxf(sacc[hf][2][1],sacc[hf][2][2]),sacc[hf][2][3]);
      float m4 = fmaxf(fmaxf(sacc[hf][3][0],sacc[hf][3][1]),sacc[hf][3][2]);
      float a  = fmaxf(fmaxf(m0,m1),m2);
      float bb = fmaxf(fmaxf(m3,m4),sacc[hf][3][3]);
      float rowmax = fmaxf(a,bb);
      rowmax = fmaxf(rowmax, __shfl_xor(rowmax, 16, 64));
      rowmax = fmaxf(rowmax, __shfl_xor(rowmax, 32, 64));
      rs[hf] = rowmax*C1;   // C1 > 0: max commutes with the scale
    }

    // defer-max over both halves (half-B domain = Mxs + w64)
    int grew = (rs[0] > Mxs + 8.0f) | (rs[1] > Mxs + w64 + 8.0f);
    if (__any(grew)){
      float Mn = fmaxf(Mxs, fmaxf(rs[0], rs[1] - w64));
      float rf = exp2f(Mxs - Mn);
      Mxs = Mn;
      float rfo[4];
      #pragma unroll
      for (int r=0;r<4;++r) rfo[r] = __shfl(rf, 4*g + r, 64);  // rf for q-local=4g+r
      #pragma unroll
      for (int n=0;n<4;++n)
        #pragma unroll
        for (int r=0;r<4;++r) oacc[n][r] *= rfo[r];
      #pragma unroll
      for (int r=0;r<4;++r) lacc[r] *= rfo[r];
    }

    // process the two halves sequentially through the per-wave P buffer
    #pragma unroll
    for (int hf=0;hf<2;++hf){
      const float mshift = (hf == 0) ? Mxs : (Mxs + w64);
      // P = exp2(s*C1 - mshift) -> bf16, 8B stores, 128B pitch
      #pragma unroll
      for (int n=0;n<4;++n){
        ushort4v w;
        #pragma unroll
        for (int r=0;r<4;++r)
          w[r] = __builtin_bit_cast(unsigned short,
                   __float2bfloat16(exp2f(fmaf(sacc[hf][n][r], C1, -mshift))));
        *(ushort4v*)(Pw + lr*128 + SWZ(lr, 32*n + 8*g)) = w;
      }
      // compiler fence: orders P stores vs PV loads (and vs prior half's
      // P reads); HW DS ops are in-order per wave, P is per-wave private.
      asm volatile("" ::: "memory");
      // O += P @ V' ; L += P @ cfrag  (rows q=4g+r, cols d=n*16+lr)
      __builtin_amdgcn_s_setprio(1);
      #pragma unroll
      for (int kk=0;kk<2;++kk){
        const int kbyte = kk*64 + g*16;
        short8 pf = *(const short8*)(Pw + lr*128 + SWZ(lr, kbyte));
        #pragma unroll
        for (int n=0;n<4;++n){
          int vrow = n*16 + lr;
          short8 vf = *(const short8*)((const char*)&Vl[cur][hf][0] + vrow*128 + SWZ(vrow, kbyte));
          mfma16(pf, vf, oacc[n]);
        }
        mfma16(pf, cfrag[kk], lacc);
      }
      __builtin_amdgcn_s_setprio(0);
      asm volatile("" ::: "memory");
    }

    // next iteration's uniform bias shift (two 64-t steps)
    Mxs += 2.0f*w64;

    // single wait+barrier per 128 t: prefetch landed, bufs safe to swap
    asm volatile("s_waitcnt vmcnt(0) lgkmcnt(0)" ::: "memory");
    __builtin_amdgcn_s_barrier();
    cur ^= 1;
  }

  // epilogue: O / L -> bf16  (row q = 4g+r, col d = n*16+lr)
  #pragma unroll
  for (int r=0;r<4;++r){
    float inv = 1.0f / lacc[r];
    int q = q0 + wave*16 + 4*g + r;
    #pragma unroll
    for (int n=0;n<4;++n){
      int d = n*16 + lr;
      Ob[(long)(b*TQ + q)*EMB + h*HD + d] = f2bf(oacc[n][r]*inv);
    }
  }
}

extern "C" void kernel_launch(void* const* d_in, const int* in_sizes, int n_in,
                              void* d_out, int out_size, void* d_ws, size_t ws_size,
                              hipStream_t stream){
  const float* x_q    = (const float*)d_in[0];
  const float* x_kv   = (const float*)d_in[1];
  const float* w_q    = (const float*)d_in[2];
  const float* w_kv   = (const float*)d_in[3];
  const float* w_proj = (const float*)d_in[4];
  const float* w_rel  = (const float*)d_in[5];
  (void)in_sizes; (void)n_in; (void)out_size; (void)ws_size;
  char* ws = (char*)d_ws;
  const size_t MB = 1024*1024;
  unsigned short* Qb   = (unsigned short*)(ws + 0);       // 8 MB
  unsigned short* Kb   = (unsigned short*)(ws + 8*MB);    // 8 MB (K only, pitch EMB)
  unsigned short* VT   = (unsigned short*)(ws + 16*MB);   // 8 MB (V' transposed, bias-baked)
  unsigned short* WpT  = (unsigned short*)(ws + 24*MB);   // 2 MB
  unsigned short* WqT  = (unsigned short*)(ws + 26*MB);   // 2 MB
  unsigned short* WkvT = (unsigned short*)(ws + 28*MB);   // 4 MB
  unsigned short* Aq   = (unsigned short*)(ws + 32*MB);   // 8 MB, dead after gemm_qkv
  unsigned short* Akv  = (unsigned short*)(ws + 40*MB);   // 8 MB, dead after gemm_qkv
  unsigned short* Ob   = Aq;    // reuse (lifetimes disjoint)
  float* out = (float*)d_out;

  prep_kernel<<<9216, 256, 0, stream>>>(x_q, x_kv, w_q, w_kv, w_proj,
                                        Aq, Akv, WqT, WkvT, WpT);
  gemm_qkv<<<dim3(24,32), 256, 0, stream>>>(Aq, WqT, Qb, Akv, WkvT, Kb, VT, w_rel);
  attn_kernel<<<dim3(16,32), 512, 0, stream>>>(Qb, Kb, VT, w_rel, Ob);
  gemm_out<<<dim3(8,64), 256, 0, stream>>>(Ob, WpT, out, NB*TQ, EMB, EMB);
}